// Round 1
// 404.290 us; speedup vs baseline: 1.0433x; 1.0433x over previous
//
#include <hip/hip_runtime.h>
#include <hip/hip_bf16.h>

// GAT layer, N=8192, F=128.
//   k0: u = W@a1, v = W@a2                     (fp32, trivial)
//   k1: Wh = h@W -> WhT (bf16 [F][N]); e_src = h@u, e_dst = h@v (fp32)
//   k2: fused masked-softmax(P) @ Wh via MFMA bf16, j split 4-ways across
//       blocks; ATOMIC-FREE: numerator -> per-seg numpart, denom -> per-seg
//       denpart (plain nontemporal stores; each block owns its slab).
//       Coalesced adj reads (q = t&15 inner), depth-2 adj/e prefetch,
//       double-buffered XOR-swizzled P tile, 1 barrier/iter.
//   k3: out[i][:] = (sum_seg numpart)/ (sum_seg denpart)
//
// ws: [0,2MB) WhT bf16 | u[128] | v[128] | e_src[8192] | e_dst[8192]
//     | denpart[4*8192] ... | [4MB,20MB) numpart[4][8192][128]

#define NN 8192
#define FF 128
#define SEG 4
#define JSEG (NN / SEG)      // 2048
#define ITERS (JSEG / 64)    // 32

typedef __bf16 bf16x8 __attribute__((ext_vector_type(8)));
typedef float floatx4 __attribute__((ext_vector_type(4)));

__device__ __forceinline__ unsigned short f2b(float f) {
    unsigned int u = __float_as_uint(f);
    return (unsigned short)((u + 0x7FFFu + ((u >> 16) & 1u)) >> 16);
}

// ---------------- k0 ----------------
__global__ __launch_bounds__(128) void k0_uv(const float* __restrict__ W,
                                             const float* __restrict__ a,
                                             float* __restrict__ u,
                                             float* __restrict__ v) {
    int k = blockIdx.x, t = threadIdx.x;
    float wv = W[k * FF + t];
    float p1 = wv * a[t];
    float p2 = wv * a[FF + t];
    for (int off = 32; off; off >>= 1) {
        p1 += __shfl_down(p1, off);
        p2 += __shfl_down(p2, off);
    }
    __shared__ float r[4];
    if ((t & 63) == 0) { r[(t >> 6) * 2] = p1; r[(t >> 6) * 2 + 1] = p2; }
    __syncthreads();
    if (t == 0) { u[k] = r[0] + r[2]; v[k] = r[1] + r[3]; }
}

// ---------------- k1 ----------------
__global__ __launch_bounds__(256) void k1_wh(const float* __restrict__ h,
                                             const float* __restrict__ W,
                                             const float* __restrict__ u,
                                             const float* __restrict__ v,
                                             unsigned short* __restrict__ WhT,
                                             float* __restrict__ e_src,
                                             float* __restrict__ e_dst) {
    __shared__ float hL[32 * 132];
    __shared__ float wL[128 * 132];
    __shared__ float uL[128], vL[128];
    __shared__ unsigned short tL[128 * 40];

    int t = threadIdx.x;
    int i0 = blockIdx.x * 32;

    {
        int row = t >> 3, c = (t & 7) * 16;
        const float4* s = (const float4*)&h[(i0 + row) * FF + c];
        float4* d = (float4*)&hL[row * 132 + c];
        #pragma unroll
        for (int j = 0; j < 4; j++) d[j] = s[j];
    }
    {
        int row = t >> 1, c = (t & 1) * 64;
        const float4* s = (const float4*)&W[row * FF + c];
        float4* d = (float4*)&wL[row * 132 + c];
        #pragma unroll
        for (int j = 0; j < 16; j++) d[j] = s[j];
    }
    if (t < 128) { uL[t] = u[t]; vL[t] = v[t]; }
    __syncthreads();

    int r0 = (t & 7) * 4;
    int c0 = (t >> 3) * 4;
    float acc[4][4] = {};
    for (int k0 = 0; k0 < 128; k0 += 4) {
        float4 hr[4], wr[4];
        #pragma unroll
        for (int i = 0; i < 4; i++) hr[i] = *(const float4*)&hL[(r0 + i) * 132 + k0];
        #pragma unroll
        for (int i = 0; i < 4; i++) wr[i] = *(const float4*)&wL[(k0 + i) * 132 + c0];
        #pragma unroll
        for (int kj = 0; kj < 4; kj++) {
            #pragma unroll
            for (int ri = 0; ri < 4; ri++) {
                float hvv = ((const float*)&hr[ri])[kj];
                const float* wvv = (const float*)&wr[kj];
                #pragma unroll
                for (int cj = 0; cj < 4; cj++) acc[ri][cj] = fmaf(hvv, wvv[cj], acc[ri][cj]);
            }
        }
    }
    #pragma unroll
    for (int ri = 0; ri < 4; ri++)
        #pragma unroll
        for (int cj = 0; cj < 4; cj++)
            tL[(c0 + cj) * 40 + r0 + ri] = f2b(acc[ri][cj]);
    __syncthreads();

    if (t < 64) {
        int row = t & 31;
        const float* sv = (t < 32) ? uL : vL;
        float s = 0.f;
        for (int k = 0; k < 128; k += 4) {
            float4 h4 = *(const float4*)&hL[row * 132 + k];
            float4 s4 = *(const float4*)&sv[k];
            s = fmaf(h4.x, s4.x, s); s = fmaf(h4.y, s4.y, s);
            s = fmaf(h4.z, s4.z, s); s = fmaf(h4.w, s4.w, s);
        }
        (t < 32 ? e_src : e_dst)[i0 + row] = s;
    }
    {
        int f = t & 127, half = t >> 7;
        const uint4* s = (const uint4*)&tL[f * 40 + half * 16];
        uint4* d = (uint4*)&WhT[f * NN + i0 + half * 16];
        d[0] = s[0]; d[1] = s[1];
    }
}

// ---------------- k2 ----------------
__device__ __forceinline__ float mask_w(int a, float x) {
    float l = fmaxf(x, 0.2f * x);
    return a > 0 ? __expf(l) : 0.f;
}

__global__ __launch_bounds__(512, 4) void k2_gat(const int* __restrict__ adj,
                                                 const unsigned short* __restrict__ WhT,
                                                 const float* __restrict__ e_src,
                                                 const float* __restrict__ e_dst,
                                                 float* __restrict__ numpart,
                                                 float* __restrict__ denpart) {
    __shared__ unsigned short wt[2][32 * 64];   // XOR-swizzled P tiles, 4 KB each
    __shared__ float esL[32];
    __shared__ float dpart[32 * 17];

    int t = threadIdx.x;
    int bx = blockIdx.x;
    int g = bx >> 2, seg = bx & 3;
    int i0 = g * 32;
    int jbase = seg * JSEG;

    if (t < 32) esL[t] = e_src[i0 + t];

    // coalesced mapping: 16 consecutive lanes sweep one row's 64 cols
    int q  = t & 15;                  // col-group (int4)
    int ii = t >> 4;                  // row 0..31
    int lane = t & 63, wave = t >> 6;
    int mrow = lane & 15, quad = lane >> 4;
    int n0 = wave * 16;

    const unsigned short* Bb = WhT + (size_t)(n0 + mrow) * NN + jbase + quad * 8;
    const int*   Ab = adj + (size_t)(i0 + ii) * NN + jbase + q * 4;
    const float* Eb = e_dst + jbase + q * 4;

    // swizzled addresses (shorts): 8-col group gg stored at gg ^ (row & 7)
    int waddr = ii * 64 + (((q >> 1) ^ (ii & 7)) << 3) + ((q & 1) << 2);
    int ra00 = mrow * 64 + ((quad ^ (mrow & 7)) << 3);
    int ra01 = mrow * 64 + (((4 + quad) ^ (mrow & 7)) << 3);
    int ra10 = (16 + mrow) * 64 + ((quad ^ (mrow & 7)) << 3);
    int ra11 = (16 + mrow) * 64 + (((4 + quad) ^ (mrow & 7)) << 3);

    floatx4 acc0 = {0.f, 0.f, 0.f, 0.f};
    floatx4 acc1 = {0.f, 0.f, 0.f, 0.f};
    float dsum = 0.f;

    // prologue: load iter 0 and iter 1 (depth-2), B fragments for iter 0
    int4   av0 = *(const int4*)Ab;
    float4 ed0 = *(const float4*)Eb;
    int4   avB = *(const int4*)(Ab + 64);
    float4 edB = *(const float4*)(Eb + 64);
    bf16x8 b0 = *(const bf16x8*)Bb;
    bf16x8 b1 = *(const bf16x8*)(Bb + 32);

    __syncthreads();
    float es_i = esL[ii];

    {
        float w0 = mask_w(av0.x, es_i + ed0.x);
        float w1 = mask_w(av0.y, es_i + ed0.y);
        float w2 = mask_w(av0.z, es_i + ed0.z);
        float w3 = mask_w(av0.w, es_i + ed0.w);
        dsum += (w0 + w1) + (w2 + w3);
        *(ushort4*)&wt[0][waddr] = make_ushort4(f2b(w0), f2b(w1), f2b(w2), f2b(w3));
    }
    __syncthreads();

    for (int k = 0; k < ITERS - 1; k++) {
        // prefetch iteration k+2 (clamped -> always in-bounds, branchless)
        int jp = ((k + 2 < ITERS) ? (k + 2) : (ITERS - 1)) * 64;
        int4   avN = *(const int4*)(Ab + jp);
        float4 edN = *(const float4*)(Eb + jp);
        int jn = (k + 1) * 64;
        bf16x8 nb0 = *(const bf16x8*)(Bb + jn);
        bf16x8 nb1 = *(const bf16x8*)(Bb + jn + 32);

        // MFMA on iteration k
        const unsigned short* buf = wt[k & 1];
        bf16x8 a00 = *(const bf16x8*)&buf[ra00];
        bf16x8 a10 = *(const bf16x8*)&buf[ra10];
        bf16x8 a01 = *(const bf16x8*)&buf[ra01];
        bf16x8 a11 = *(const bf16x8*)&buf[ra11];
        acc0 = __builtin_amdgcn_mfma_f32_16x16x32_bf16(a00, b0, acc0, 0, 0, 0);
        acc1 = __builtin_amdgcn_mfma_f32_16x16x32_bf16(a10, b0, acc1, 0, 0, 0);
        acc0 = __builtin_amdgcn_mfma_f32_16x16x32_bf16(a01, b1, acc0, 0, 0, 0);
        acc1 = __builtin_amdgcn_mfma_f32_16x16x32_bf16(a11, b1, acc1, 0, 0, 0);

        // compute iteration k+1 weights -> other buffer (uses depth-2 slot)
        float w0 = mask_w(avB.x, es_i + edB.x);
        float w1 = mask_w(avB.y, es_i + edB.y);
        float w2 = mask_w(avB.z, es_i + edB.z);
        float w3 = mask_w(avB.w, es_i + edB.w);
        dsum += (w0 + w1) + (w2 + w3);
        *(ushort4*)&wt[(k + 1) & 1][waddr] = make_ushort4(f2b(w0), f2b(w1), f2b(w2), f2b(w3));
        avB = avN; edB = edN;
        b0 = nb0; b1 = nb1;
        __syncthreads();
    }
    {
        const unsigned short* buf = wt[(ITERS - 1) & 1];
        bf16x8 a00 = *(const bf16x8*)&buf[ra00];
        bf16x8 a10 = *(const bf16x8*)&buf[ra10];
        bf16x8 a01 = *(const bf16x8*)&buf[ra01];
        bf16x8 a11 = *(const bf16x8*)&buf[ra11];
        acc0 = __builtin_amdgcn_mfma_f32_16x16x32_bf16(a00, b0, acc0, 0, 0, 0);
        acc1 = __builtin_amdgcn_mfma_f32_16x16x32_bf16(a10, b0, acc1, 0, 0, 0);
        acc0 = __builtin_amdgcn_mfma_f32_16x16x32_bf16(a01, b1, acc0, 0, 0, 0);
        acc1 = __builtin_amdgcn_mfma_f32_16x16x32_bf16(a11, b1, acc1, 0, 0, 0);
    }

    dpart[ii * 17 + q] = dsum;
    __syncthreads();
    if (t < 32) {
        float s = 0.f;
        #pragma unroll
        for (int k = 0; k < 16; k++) s += dpart[t * 17 + k];
        __builtin_nontemporal_store(s, &denpart[seg * NN + i0 + t]);
    }

    // numerator: plain per-seg stores (no atomics; block owns its slab)
    // C/D layout col=lane&15, row=(lane>>4)*4+reg
    float* np = numpart + (size_t)seg * NN * FF;
    #pragma unroll
    for (int r = 0; r < 4; r++) {
        int row0 = quad * 4 + r;
        __builtin_nontemporal_store(acc0[r], &np[(size_t)(i0 + row0) * FF + n0 + mrow]);
        __builtin_nontemporal_store(acc1[r], &np[(size_t)(i0 + 16 + row0) * FF + n0 + mrow]);
    }
}

// ---------------- k3: out[i][:] = sum_seg(num)/sum_seg(den) ----------------
__global__ __launch_bounds__(256) void k3_merge(const float* __restrict__ np,
                                               const float* __restrict__ dp,
                                               float* __restrict__ out) {
    int idx = blockIdx.x * 256 + threadIdx.x;   // one float4 each
    int i = idx >> 5;
    int c = (idx & 31) << 2;
    float d = dp[i] + dp[NN + i] + dp[2 * NN + i] + dp[3 * NN + i];
    float r = 1.0f / d;
    size_t o = (size_t)i * FF + c;
    const size_t S = (size_t)NN * FF;
    float4 a0 = *(const float4*)&np[o];
    float4 a1 = *(const float4*)&np[o + S];
    float4 a2 = *(const float4*)&np[o + 2 * S];
    float4 a3 = *(const float4*)&np[o + 3 * S];
    float4 v;
    v.x = ((a0.x + a1.x) + (a2.x + a3.x)) * r;
    v.y = ((a0.y + a1.y) + (a2.y + a3.y)) * r;
    v.z = ((a0.z + a1.z) + (a2.z + a3.z)) * r;
    v.w = ((a0.w + a1.w) + (a2.w + a3.w)) * r;
    *(float4*)&out[o] = v;
}

extern "C" void kernel_launch(void* const* d_in, const int* in_sizes, int n_in,
                              void* d_out, int out_size, void* d_ws, size_t ws_size,
                              hipStream_t stream) {
    const float* h   = (const float*)d_in[0];
    const int*   adj = (const int*)d_in[1];
    const float* W   = (const float*)d_in[2];
    const float* a   = (const float*)d_in[3];
    float* out = (float*)d_out;

    char* ws = (char*)d_ws;
    unsigned short* WhT = (unsigned short*)ws;              // 2 MB bf16 [F][N]
    float* u     = (float*)(ws + 2097152);
    float* v     = u + 128;
    float* e_src = v + 128;
    float* e_dst = e_src + NN;
    float* denpart = e_dst + NN;                            // 4*NN floats = 128 KB
    float* numpart = (float*)(ws + (4u << 20));             // [4MB,20MB) 4*N*F

    k0_uv<<<dim3(128), dim3(128), 0, stream>>>(W, a, u, v);
    k1_wh<<<dim3(256), dim3(256), 0, stream>>>(h, W, u, v, WhT, e_src, e_dst);
    k2_gat<<<dim3(256 * SEG), dim3(512), 0, stream>>>(adj, WhT, e_src, e_dst, numpart, denpart);
    k3_merge<<<dim3(NN * FF / 4 / 256), dim3(256), 0, stream>>>(numpart, denpart, out);
}

// Round 3
// 397.793 us; speedup vs baseline: 1.0603x; 1.0163x over previous
//
#include <hip/hip_runtime.h>
#include <hip/hip_bf16.h>

// GAT layer, N=8192, F=128.
//   k1: Wh = h@W -> WhT (bf16 [F][N]); u/v computed in-block (k0 folded);
//       e_src = (h@u)/ln2, e_dst = (h@v)/ln2 (pre-scaled for exp2 in k2).
//       512 threads/block (8 waves/CU vs 4 before).
//   k2: fused masked-softmax(P) @ Wh via MFMA bf16, j split 4-ways across
//       blocks; atomic-free per-seg numpart/denpart slabs; coalesced
//       nontemporal adj reads, depth-2 prefetch, double-buffered
//       XOR-swizzled P tile, 1 barrier/iter; exp2 + cvt_pk bf16 packing.
//   k3: out[i][:] = (sum_seg numpart)/(sum_seg denpart)
//
// ws: [0,2MB) WhT bf16 | e_src[8192] | e_dst[8192] | denpart[4*8192]
//     | [4MB,20MB) numpart[4][8192][128]

#define NN 8192
#define FF 128
#define SEG 4
#define JSEG (NN / SEG)      // 2048
#define ITERS (JSEG / 64)    // 32

typedef __bf16 bf16x8 __attribute__((ext_vector_type(8)));
typedef float floatx4 __attribute__((ext_vector_type(4)));
typedef int   intx4  __attribute__((ext_vector_type(4)));   // clang ext-vector: OK for nontemporal builtin

__device__ __forceinline__ unsigned short b2u(__bf16 x) {
    return __builtin_bit_cast(unsigned short, x);
}

// ---------------- k1 ----------------
__global__ __launch_bounds__(512) void k1_wh(const float* __restrict__ h,
                                             const float* __restrict__ W,
                                             const float* __restrict__ a,
                                             unsigned short* __restrict__ WhT,
                                             float* __restrict__ e_src,
                                             float* __restrict__ e_dst) {
    __shared__ float hL[32 * 132];
    __shared__ float wL[128 * 132];
    __shared__ float uL[128], vL[128];
    __shared__ unsigned short tL[128 * 40];

    int t = threadIdx.x;
    int i0 = blockIdx.x * 32;

    {   // h tile: 32 x 128, 8 floats/thread
        int row = t >> 4, c = (t & 15) * 8;
        const float4* s = (const float4*)&h[(i0 + row) * FF + c];
        float4* d = (float4*)&hL[row * 132 + c];
        d[0] = s[0]; d[1] = s[1];
    }
    {   // W: 128 x 128, 32 floats/thread
        int row = t >> 2, c = (t & 3) * 32;
        const float4* s = (const float4*)&W[row * FF + c];
        float4* d = (float4*)&wL[row * 132 + c];
        #pragma unroll
        for (int j = 0; j < 8; j++) d[j] = s[j];
    }
    __syncthreads();

    // fold k0: u = (W@a1)/ln2, v = (W@a2)/ln2 computed per block
    if (t < 256) {
        int k = t & 127;
        const float* ap = a + (t >> 7) * FF;
        float s = 0.f;
        for (int c = 0; c < 128; c += 4) {
            float4 w4 = *(const float4*)&wL[k * 132 + c];
            s = fmaf(w4.x, ap[c], s);     s = fmaf(w4.y, ap[c + 1], s);
            s = fmaf(w4.z, ap[c + 2], s); s = fmaf(w4.w, ap[c + 3], s);
        }
        (t < 128 ? uL : vL)[k] = s * 1.44269504f;
    }

    // main matmul: each thread 4 rows x 2 cols
    int r0 = (t & 7) * 4;
    int c0 = (t >> 3) * 2;
    float acc[4][2] = {};
    for (int k0 = 0; k0 < 128; k0 += 4) {
        float4 hr[4]; float2 wr[4];
        #pragma unroll
        for (int i = 0; i < 4; i++) hr[i] = *(const float4*)&hL[(r0 + i) * 132 + k0];
        #pragma unroll
        for (int i = 0; i < 4; i++) wr[i] = *(const float2*)&wL[(k0 + i) * 132 + c0];
        #pragma unroll
        for (int kj = 0; kj < 4; kj++) {
            #pragma unroll
            for (int ri = 0; ri < 4; ri++) {
                float hvv = ((const float*)&hr[ri])[kj];
                acc[ri][0] = fmaf(hvv, wr[kj].x, acc[ri][0]);
                acc[ri][1] = fmaf(hvv, wr[kj].y, acc[ri][1]);
            }
        }
    }
    #pragma unroll
    for (int ri = 0; ri < 4; ri++)
        #pragma unroll
        for (int cj = 0; cj < 2; cj++)
            tL[(c0 + cj) * 40 + r0 + ri] = b2u((__bf16)acc[ri][cj]);
    __syncthreads();

    if (t < 64) {
        int row = t & 31;
        const float* sv = (t < 32) ? uL : vL;
        float s = 0.f;
        for (int k = 0; k < 128; k += 4) {
            float4 h4 = *(const float4*)&hL[row * 132 + k];
            float4 s4 = *(const float4*)&sv[k];
            s = fmaf(h4.x, s4.x, s); s = fmaf(h4.y, s4.y, s);
            s = fmaf(h4.z, s4.z, s); s = fmaf(h4.w, s4.w, s);
        }
        (t < 32 ? e_src : e_dst)[i0 + row] = s;
    }
    {   // WhT store: 512 threads x 8 shorts
        int f = t & 127, part = t >> 7;
        const uint4* s = (const uint4*)&tL[f * 40 + part * 8];
        uint4* d = (uint4*)&WhT[f * NN + i0 + part * 8];
        *d = *s;
    }
}

// ---------------- k2 ----------------
__device__ __forceinline__ float mask_w(int a, float x) {
    // x is pre-scaled by 1/ln2; leaky commutes with positive scale
    float l = fmaxf(x, 0.2f * x);
    float e = __builtin_amdgcn_exp2f(l);
    return a > 0 ? e : 0.f;
}

__device__ __forceinline__ ushort4 pack4(float w0, float w1, float w2, float w3) {
    union { ushort4 u; __bf16 b[4]; } pk;
    pk.b[0] = (__bf16)w0; pk.b[1] = (__bf16)w1;
    pk.b[2] = (__bf16)w2; pk.b[3] = (__bf16)w3;
    return pk.u;
}

__global__ __launch_bounds__(512, 4) void k2_gat(const int* __restrict__ adj,
                                                 const unsigned short* __restrict__ WhT,
                                                 const float* __restrict__ e_src,
                                                 const float* __restrict__ e_dst,
                                                 float* __restrict__ numpart,
                                                 float* __restrict__ denpart) {
    __shared__ unsigned short wt[2][32 * 64];   // XOR-swizzled P tiles, 4 KB each
    __shared__ float esL[32];
    __shared__ float dpart[32 * 17];

    int t = threadIdx.x;
    int bx = blockIdx.x;
    int g = bx >> 2, seg = bx & 3;
    int i0 = g * 32;
    int jbase = seg * JSEG;

    if (t < 32) esL[t] = e_src[i0 + t];

    // coalesced mapping: 16 consecutive lanes sweep one row's 64 cols
    int q  = t & 15;                  // col-group (int4)
    int ii = t >> 4;                  // row 0..31
    int lane = t & 63, wave = t >> 6;
    int mrow = lane & 15, quad = lane >> 4;
    int n0 = wave * 16;

    const unsigned short* Bb = WhT + (size_t)(n0 + mrow) * NN + jbase + quad * 8;
    const intx4* Ab = (const intx4*)(adj + (size_t)(i0 + ii) * NN + jbase + q * 4);
    const float* Eb = e_dst + jbase + q * 4;

    // swizzled addresses (shorts): 8-col group gg stored at gg ^ (row & 7)
    int waddr = ii * 64 + (((q >> 1) ^ (ii & 7)) << 3) + ((q & 1) << 2);
    int ra00 = mrow * 64 + ((quad ^ (mrow & 7)) << 3);
    int ra01 = mrow * 64 + (((4 + quad) ^ (mrow & 7)) << 3);
    int ra10 = (16 + mrow) * 64 + ((quad ^ (mrow & 7)) << 3);
    int ra11 = (16 + mrow) * 64 + (((4 + quad) ^ (mrow & 7)) << 3);

    floatx4 acc0 = {0.f, 0.f, 0.f, 0.f};
    floatx4 acc1 = {0.f, 0.f, 0.f, 0.f};
    float dsum = 0.f;

    // prologue: load iter 0 and iter 1 (depth-2), B fragments for iter 0
    // adj advances 16 ints per iter step of 64 cols? No: Ab is intx4*, +16 per 64 cols.
    intx4  av0 = __builtin_nontemporal_load(Ab);
    float4 ed0 = *(const float4*)Eb;
    intx4  avB = __builtin_nontemporal_load(Ab + 16);
    float4 edB = *(const float4*)(Eb + 64);
    bf16x8 b0 = *(const bf16x8*)Bb;
    bf16x8 b1 = *(const bf16x8*)(Bb + 32);

    __syncthreads();
    float es_i = esL[ii];

    {
        float w0 = mask_w(av0.x, es_i + ed0.x);
        float w1 = mask_w(av0.y, es_i + ed0.y);
        float w2 = mask_w(av0.z, es_i + ed0.z);
        float w3 = mask_w(av0.w, es_i + ed0.w);
        dsum += (w0 + w1) + (w2 + w3);
        *(ushort4*)&wt[0][waddr] = pack4(w0, w1, w2, w3);
    }
    __syncthreads();

    for (int k = 0; k < ITERS - 1; k++) {
        // prefetch iteration k+2 (clamped -> always in-bounds, branchless)
        int jp = ((k + 2 < ITERS) ? (k + 2) : (ITERS - 1));
        intx4  avN = __builtin_nontemporal_load(Ab + jp * 16);
        float4 edN = *(const float4*)(Eb + jp * 64);
        int jn = (k + 1) * 64;
        bf16x8 nb0 = *(const bf16x8*)(Bb + jn);
        bf16x8 nb1 = *(const bf16x8*)(Bb + jn + 32);

        // MFMA on iteration k
        const unsigned short* buf = wt[k & 1];
        bf16x8 a00 = *(const bf16x8*)&buf[ra00];
        bf16x8 a10 = *(const bf16x8*)&buf[ra10];
        bf16x8 a01 = *(const bf16x8*)&buf[ra01];
        bf16x8 a11 = *(const bf16x8*)&buf[ra11];
        acc0 = __builtin_amdgcn_mfma_f32_16x16x32_bf16(a00, b0, acc0, 0, 0, 0);
        acc1 = __builtin_amdgcn_mfma_f32_16x16x32_bf16(a10, b0, acc1, 0, 0, 0);
        acc0 = __builtin_amdgcn_mfma_f32_16x16x32_bf16(a01, b1, acc0, 0, 0, 0);
        acc1 = __builtin_amdgcn_mfma_f32_16x16x32_bf16(a11, b1, acc1, 0, 0, 0);

        // compute iteration k+1 weights -> other buffer (uses depth-2 slot)
        float w0 = mask_w(avB.x, es_i + edB.x);
        float w1 = mask_w(avB.y, es_i + edB.y);
        float w2 = mask_w(avB.z, es_i + edB.z);
        float w3 = mask_w(avB.w, es_i + edB.w);
        dsum += (w0 + w1) + (w2 + w3);
        *(ushort4*)&wt[(k + 1) & 1][waddr] = pack4(w0, w1, w2, w3);
        avB = avN; edB = edN;
        b0 = nb0; b1 = nb1;
        __syncthreads();
    }
    {
        const unsigned short* buf = wt[(ITERS - 1) & 1];
        bf16x8 a00 = *(const bf16x8*)&buf[ra00];
        bf16x8 a10 = *(const bf16x8*)&buf[ra10];
        bf16x8 a01 = *(const bf16x8*)&buf[ra01];
        bf16x8 a11 = *(const bf16x8*)&buf[ra11];
        acc0 = __builtin_amdgcn_mfma_f32_16x16x32_bf16(a00, b0, acc0, 0, 0, 0);
        acc1 = __builtin_amdgcn_mfma_f32_16x16x32_bf16(a10, b0, acc1, 0, 0, 0);
        acc0 = __builtin_amdgcn_mfma_f32_16x16x32_bf16(a01, b1, acc0, 0, 0, 0);
        acc1 = __builtin_amdgcn_mfma_f32_16x16x32_bf16(a11, b1, acc1, 0, 0, 0);
    }

    dpart[ii * 17 + q] = dsum;
    __syncthreads();
    if (t < 32) {
        float s = 0.f;
        #pragma unroll
        for (int k = 0; k < 16; k++) s += dpart[t * 17 + k];
        __builtin_nontemporal_store(s, &denpart[seg * NN + i0 + t]);
    }

    // numerator: plain per-seg stores (no atomics; block owns its slab)
    // C/D layout col=lane&15, row=(lane>>4)*4+reg
    float* np = numpart + (size_t)seg * NN * FF;
    #pragma unroll
    for (int r = 0; r < 4; r++) {
        int row0 = quad * 4 + r;
        __builtin_nontemporal_store(acc0[r], &np[(size_t)(i0 + row0) * FF + n0 + mrow]);
        __builtin_nontemporal_store(acc1[r], &np[(size_t)(i0 + 16 + row0) * FF + n0 + mrow]);
    }
}

// ---------------- k3: out[i][:] = sum_seg(num)/sum_seg(den) ----------------
__global__ __launch_bounds__(256) void k3_merge(const float* __restrict__ np,
                                               const float* __restrict__ dp,
                                               float* __restrict__ out) {
    int idx = blockIdx.x * 256 + threadIdx.x;   // one float4 each
    int i = idx >> 5;
    int c = (idx & 31) << 2;
    float d = dp[i] + dp[NN + i] + dp[2 * NN + i] + dp[3 * NN + i];
    float r = 1.0f / d;
    size_t o = (size_t)i * FF + c;
    const size_t S = (size_t)NN * FF;
    float4 a0 = *(const float4*)&np[o];
    float4 a1 = *(const float4*)&np[o + S];
    float4 a2 = *(const float4*)&np[o + 2 * S];
    float4 a3 = *(const float4*)&np[o + 3 * S];
    float4 v;
    v.x = ((a0.x + a1.x) + (a2.x + a3.x)) * r;
    v.y = ((a0.y + a1.y) + (a2.y + a3.y)) * r;
    v.z = ((a0.z + a1.z) + (a2.z + a3.z)) * r;
    v.w = ((a0.w + a1.w) + (a2.w + a3.w)) * r;
    *(float4*)&out[o] = v;
}

extern "C" void kernel_launch(void* const* d_in, const int* in_sizes, int n_in,
                              void* d_out, int out_size, void* d_ws, size_t ws_size,
                              hipStream_t stream) {
    const float* h   = (const float*)d_in[0];
    const int*   adj = (const int*)d_in[1];
    const float* W   = (const float*)d_in[2];
    const float* a   = (const float*)d_in[3];
    float* out = (float*)d_out;

    char* ws = (char*)d_ws;
    unsigned short* WhT = (unsigned short*)ws;              // 2 MB bf16 [F][N]
    float* e_src = (float*)(ws + 2097152);
    float* e_dst = e_src + NN;
    float* denpart = e_dst + NN;                            // 4*NN floats = 128 KB
    float* numpart = (float*)(ws + (4u << 20));             // [4MB,20MB) 4*N*F

    k1_wh<<<dim3(256), dim3(512), 0, stream>>>(h, W, a, WhT, e_src, e_dst);
    k2_gat<<<dim3(256 * SEG), dim3(512), 0, stream>>>(adj, WhT, e_src, e_dst, numpart, denpart);
    k3_merge<<<dim3(NN * FF / 4 / 256), dim3(256), 0, stream>>>(numpart, denpart, out);
}